// Round 4
// baseline (164.398 us; speedup 1.0000x reference)
//
#include <hip/hip_runtime.h>
#include <math.h>

// ---------------------------------------------------------------------------
// AsymQuantMatMul: A[4096,2048] fp32, B[2048,4096] fp32 -> out[4096,4096] fp32
// R3: 3 launches (minmax partials -> fused quant -> gemm).
//     GEMM uses mfma_i32_32x32x32_i8 (2x2 frags of 32x32 per wave = 64x64),
//     128x128 block, BK=128, 3-bit XOR LDS swizzle, XCD L2 regioning,
//     nontemporal output stores. Fused quant: every block re-reduces the
//     1024 minmax partials itself (kills the grid-1 stage2 bubble).
// ---------------------------------------------------------------------------

#define M_DIM 4096
#define K_DIM 2048
#define N_DIM 4096

using int4v = __attribute__((ext_vector_type(4))) int;
using int16v = __attribute__((ext_vector_type(16))) int;

typedef __attribute__((address_space(1))) const void glb_cv;
typedef __attribute__((address_space(3))) void lds_v;

__device__ __forceinline__ int qbyte(float x, float rs, float z) {
    // reference: clip(round(x/scale) + zero, 0, 255), shifted by -128
    float q = fminf(fmaxf(rintf(x * rs) + z, 0.0f), 255.0f);
    return (int)q - 128;
}

__device__ __forceinline__ int sum4(int w) {
    return (int)(signed char)(w) + (int)(signed char)(w >> 8) +
           (int)(signed char)(w >> 16) + (int)(signed char)(w >> 24);
}

// ---- Kernel 1: per-block min/max partials (512 A + 512 B); zero colB ----
__global__ void minmax_stage1(const float* __restrict__ A,
                              const float* __restrict__ B,
                              float* __restrict__ partials,
                              int* __restrict__ colB) {
    int b = blockIdx.x;
    if (b < 16) colB[b * 256 + threadIdx.x] = 0;  // init for quant atomics
    const float* src = (b < 512) ? A : B;
    int lb = (b < 512) ? b : b - 512;
    const float4* v = (const float4*)src + (long)lb * 4096;  // 4096 float4/block
    float mn = INFINITY, mx = -INFINITY;
    for (int i = threadIdx.x; i < 4096; i += 256) {
        float4 x = v[i];
        mn = fminf(mn, fminf(fminf(x.x, x.y), fminf(x.z, x.w)));
        mx = fmaxf(mx, fmaxf(fmaxf(x.x, x.y), fmaxf(x.z, x.w)));
    }
    for (int off = 32; off; off >>= 1) {
        mn = fminf(mn, __shfl_down(mn, off));
        mx = fmaxf(mx, __shfl_down(mx, off));
    }
    __shared__ float smn[4], smx[4];
    int w = threadIdx.x >> 6;
    if ((threadIdx.x & 63) == 0) { smn[w] = mn; smx[w] = mx; }
    __syncthreads();
    if (threadIdx.x == 0) {
        mn = fminf(fminf(smn[0], smn[1]), fminf(smn[2], smn[3]));
        mx = fmaxf(fmaxf(smx[0], smx[1]), fmaxf(smx[2], smx[3]));
        partials[2 * b] = mn;
        partials[2 * b + 1] = mx;
    }
}

// ---- Kernel 2: fused quantize. Blocks 0..2047: A (2 rows each, row-major
// i8, + row sums). Blocks 2048..4095: B 64x64 tile transpose (+ col sums).
// Every block deterministically re-reduces all partials -> identical qp.
__global__ void quant_fused(const float* __restrict__ A,
                            const float* __restrict__ B,
                            const float* __restrict__ partials,
                            signed char* __restrict__ A8,
                            signed char* __restrict__ B8T,
                            int* __restrict__ rowA,
                            int* __restrict__ colB,
                            float* __restrict__ qp) {
    int b = blockIdx.x, t = threadIdx.x;

    // -- reduce all 1024 partial pairs (L2/L3-cached after kernel 1) --
    float mnA = INFINITY, mxA = -INFINITY, mnB = INFINITY, mxB = -INFINITY;
    for (int i = t; i < 512; i += 256) {
        mnA = fminf(mnA, partials[2 * i]);
        mxA = fmaxf(mxA, partials[2 * i + 1]);
        mnB = fminf(mnB, partials[2 * (i + 512)]);
        mxB = fmaxf(mxB, partials[2 * (i + 512) + 1]);
    }
    for (int off = 32; off; off >>= 1) {
        mnA = fminf(mnA, __shfl_down(mnA, off));
        mxA = fmaxf(mxA, __shfl_down(mxA, off));
        mnB = fminf(mnB, __shfl_down(mnB, off));
        mxB = fmaxf(mxB, __shfl_down(mxB, off));
    }
    __shared__ float sred[4][4];
    int w = t >> 6;
    if ((t & 63) == 0) { sred[w][0] = mnA; sred[w][1] = mxA; sred[w][2] = mnB; sred[w][3] = mxB; }
    __syncthreads();
    mnA = fminf(fminf(sred[0][0], sred[1][0]), fminf(sred[2][0], sred[3][0]));
    mxA = fmaxf(fmaxf(sred[0][1], sred[1][1]), fmaxf(sred[2][1], sred[3][1]));
    mnB = fminf(fminf(sred[0][2], sred[1][2]), fminf(sred[2][2], sred[3][2]));
    mxB = fmaxf(fmaxf(sred[0][3], sred[1][3]), fmaxf(sred[2][3], sred[3][3]));
    float sA = (mxA - mnA) / 255.0f;
    float zA = rintf(-mnA / sA);
    float sB = (mxB - mnB) / 255.0f;
    float zB = rintf(-mnB / sB);
    if (b == 0 && t == 0) { qp[0] = sA; qp[1] = zA; qp[2] = sB; qp[3] = zB; }
    __syncthreads();  // sred reuse barrier (B path tile is separate but be safe)

    if (b < 2048) {
        // ---- A path: 2 rows of 2048, fused row sums ----
        float rs = 1.0f / sA, z = zA;
        long base = (long)b * 4096 + (long)t * 16;
        const float4* v = (const float4*)(A + base);
        union { signed char c[16]; int4 i4; } u;
        int ls = 0;
#pragma unroll
        for (int j = 0; j < 4; j++) {
            float4 x = v[j];
            int q0 = qbyte(x.x, rs, z), q1 = qbyte(x.y, rs, z);
            int q2 = qbyte(x.z, rs, z), q3 = qbyte(x.w, rs, z);
            u.c[j * 4 + 0] = (signed char)q0;
            u.c[j * 4 + 1] = (signed char)q1;
            u.c[j * 4 + 2] = (signed char)q2;
            u.c[j * 4 + 3] = (signed char)q3;
            ls += q0 + q1 + q2 + q3;
        }
        *(int4*)(A8 + base) = u.i4;
        for (int off = 32; off; off >>= 1) ls += __shfl_down(ls, off);
        __shared__ int wsum[4];
        if ((t & 63) == 0) wsum[t >> 6] = ls;
        __syncthreads();
        if (t == 0) rowA[b * 2] = wsum[0] + wsum[1];
        if (t == 128) rowA[b * 2 + 1] = wsum[2] + wsum[3];
    } else {
        // ---- B path: 64x64 tile transpose via int-packed LDS, col sums ----
        float rs = 1.0f / sB, z = zB;
        int bb = b - 2048;
        int k0 = (bb & 31) * 64, n0 = (bb >> 5) * 64;
        __shared__ int tile[64][17];  // [n][k/4], +1 pad
        int cn = (t & 15) * 4;  // n offset within tile
        int kg = (t >> 4) * 4;  // k offset within tile
        int w0 = 0, w1 = 0, w2 = 0, w3 = 0;
#pragma unroll
        for (int r = 0; r < 4; r++) {
            float4 x = *(const float4*)&B[(long)(k0 + kg + r) * N_DIM + n0 + cn];
            w0 |= (qbyte(x.x, rs, z) & 255) << (8 * r);
            w1 |= (qbyte(x.y, rs, z) & 255) << (8 * r);
            w2 |= (qbyte(x.z, rs, z) & 255) << (8 * r);
            w3 |= (qbyte(x.w, rs, z) & 255) << (8 * r);
        }
        int kc = kg >> 2;
        tile[cn + 0][kc] = w0;
        tile[cn + 1][kc] = w1;
        tile[cn + 2][kc] = w2;
        tile[cn + 3][kc] = w3;
        __syncthreads();
        int n2 = t >> 2, kb = (t & 3) * 4;
        int4 v;
        v.x = tile[n2][kb + 0];
        v.y = tile[n2][kb + 1];
        v.z = tile[n2][kb + 2];
        v.w = tile[n2][kb + 3];
        *(int4*)&B8T[(long)(n0 + n2) * K_DIM + k0 + (t & 3) * 16] = v;
        int ls = sum4(v.x) + sum4(v.y) + sum4(v.z) + sum4(v.w);
        ls += __shfl_down(ls, 2);
        ls += __shfl_down(ls, 1);
        if ((t & 3) == 0) atomicAdd(&colB[n0 + n2], ls);
    }
}

// ---- Kernel 3: i8 MFMA GEMM, 32x32x32 shape ----
// 128x128 block, BK=128, 4 waves each 64x64 (2x2 frags of 32x32).
// LDS: 16B chunk c of row r stored at slot c ^ (r&7) (3-bit XOR swizzle).
// Block->tile: 16 regions of 8x8 tiles keyed to XCD for L2 locality.
__global__ __launch_bounds__(256, 3) void gemm_i8(
        const signed char* __restrict__ A8,
        const signed char* __restrict__ B8T,
        const int* __restrict__ rowA,
        const int* __restrict__ colB,
        const float* __restrict__ qp,
        float* __restrict__ out) {
    __shared__ __align__(16) signed char As[128 * 128];  // 16 KB
    __shared__ __align__(16) signed char Bs[128 * 128];  // 16 KB

    // L2-locality block swizzle
    int b = blockIdx.x;
    int xcd = b & 7, i0 = b >> 3;
    int reg = xcd + 8 * (i0 >> 6);    // region 0..15
    int jj0 = i0 & 63;                // 0..63 within region
    int mt = (reg >> 2) * 8 + (jj0 >> 3);
    int nt = (reg & 3) * 8 + (jj0 & 7);
    int r0 = mt * 128, c0 = nt * 128;

    int t = threadIdx.x, lane = t & 63, wave = t >> 6;
    int l31 = lane & 31;
    int lh = lane >> 5;              // k-half 0..1
    int wm = (wave >> 1) * 64;       // wave m offset
    int wn = (wave & 1) * 64;        // wave n offset

    int16v acc[2][2];
#pragma unroll
    for (int i = 0; i < 2; i++)
#pragma unroll
        for (int j = 0; j < 2; j++)
#pragma unroll
            for (int r = 0; r < 16; r++) acc[i][j][r] = 0;

    // Staging offsets: LDS chunk ch -> row=ch>>3, slot p=ch&7 holds global
    // chunk p ^ (row&7).
    long aoff[4], boff[4];
#pragma unroll
    for (int j = 0; j < 4; j++) {
        int ch = t + 256 * j;        // 0..1023
        int row = ch >> 3, p = ch & 7;
        int gk = p ^ (row & 7);
        aoff[j] = (long)(r0 + row) * K_DIM + gk * 16;
        boff[j] = (long)(c0 + row) * K_DIM + gk * 16;
    }

    // Fragment rows (fixed per lane) and their swizzle keys
    int arow0 = wm + l31, arow1 = wm + 32 + l31;
    int brow0 = wn + l31, brow1 = wn + 32 + l31;

    for (int k0 = 0; k0 < K_DIM; k0 += 128) {
        __syncthreads();  // protect LDS from previous iteration's readers
#pragma unroll
        for (int j = 0; j < 4; j++)
            __builtin_amdgcn_global_load_lds((glb_cv*)(A8 + aoff[j] + k0),
                                             (lds_v*)(As + (t + 256 * j) * 16), 16, 0, 0);
#pragma unroll
        for (int j = 0; j < 4; j++)
            __builtin_amdgcn_global_load_lds((glb_cv*)(B8T + boff[j] + k0),
                                             (lds_v*)(Bs + (t + 256 * j) * 16), 16, 0, 0);
        __syncthreads();  // staged data visible

#pragma unroll
        for (int ks = 0; ks < 4; ks++) {
            int c = ks * 2 + lh;     // global 16B chunk index within row
            int4v af0 = *(const int4v*)&As[arow0 * 128 + ((c ^ (arow0 & 7)) * 16)];
            int4v af1 = *(const int4v*)&As[arow1 * 128 + ((c ^ (arow1 & 7)) * 16)];
            int4v bf0 = *(const int4v*)&Bs[brow0 * 128 + ((c ^ (brow0 & 7)) * 16)];
            int4v bf1 = *(const int4v*)&Bs[brow1 * 128 + ((c ^ (brow1 & 7)) * 16)];
            acc[0][0] = __builtin_amdgcn_mfma_i32_32x32x32_i8(af0, bf0, acc[0][0], 0, 0, 0);
            acc[0][1] = __builtin_amdgcn_mfma_i32_32x32x32_i8(af0, bf1, acc[0][1], 0, 0, 0);
            acc[1][0] = __builtin_amdgcn_mfma_i32_32x32x32_i8(af1, bf0, acc[1][0], 0, 0, 0);
            acc[1][1] = __builtin_amdgcn_mfma_i32_32x32x32_i8(af1, bf1, acc[1][1], 0, 0, 0);
        }
    }

    // Epilogue: out = sA*sB*(acc + cB*rowA[m] + cA*colB[n] + K*cA*cB)
    // C/D layout (32x32, verified): col=lane&31, row=(reg&3)+8*(reg>>2)+4*(lane>>5)
    float sA = qp[0], zA = qp[1], sB = qp[2], zB = qp[3];
    int cA = 128 - (int)zA, cB = 128 - (int)zB;
    float ss = sA * sB;
    int Kzz = K_DIM * cA * cB;
#pragma unroll
    for (int fm = 0; fm < 2; fm++) {
        int rbase = r0 + wm + fm * 32 + 4 * lh;
        int ra[16];
#pragma unroll
        for (int rq = 0; rq < 4; rq++) {
            int4 rv = *(const int4*)&rowA[rbase + 8 * rq];
            ra[rq * 4 + 0] = cB * rv.x + Kzz;
            ra[rq * 4 + 1] = cB * rv.y + Kzz;
            ra[rq * 4 + 2] = cB * rv.z + Kzz;
            ra[rq * 4 + 3] = cB * rv.w + Kzz;
        }
#pragma unroll
        for (int fn = 0; fn < 2; fn++) {
            int cc = c0 + wn + fn * 32 + l31;
            int can = cA * colB[cc];
#pragma unroll
            for (int r = 0; r < 16; r++) {
                int row = rbase + (r & 3) + 8 * (r >> 2);
                int v = acc[fm][fn][r] + ra[(r >> 2) * 4 + (r & 3)] + can;
                __builtin_nontemporal_store(ss * (float)v, &out[(long)row * N_DIM + cc]);
            }
        }
    }
}

extern "C" void kernel_launch(void* const* d_in, const int* in_sizes, int n_in,
                              void* d_out, int out_size, void* d_ws, size_t ws_size,
                              hipStream_t stream) {
    const float* A = (const float*)d_in[0];
    const float* B = (const float*)d_in[1];
    float* out = (float*)d_out;
    char* ws = (char*)d_ws;

    signed char* A8  = (signed char*)ws;                    //  8 MB
    signed char* B8T = (signed char*)(ws + 8388608);        //  8 MB
    int*   rowA      = (int*)(ws + 16777216);               // 16 KB
    int*   colB      = (int*)(ws + 16793600);               // 16 KB
    float* partials  = (float*)(ws + 16809984);             //  8 KB
    float* qp        = (float*)(ws + 16818176);             // 16 B

    minmax_stage1<<<1024, 256, 0, stream>>>(A, B, partials, colB);
    quant_fused<<<4096, 256, 0, stream>>>(A, B, partials, A8, B8T, rowA, colB, qp);
    gemm_i8<<<1024, 256, 0, stream>>>(A8, B8T, rowA, colB, qp, out);
}

// Round 5
// 162.053 us; speedup vs baseline: 1.0145x; 1.0145x over previous
//
#include <hip/hip_runtime.h>
#include <math.h>

// ---------------------------------------------------------------------------
// AsymQuantMatMul: A[4096,2048] fp32, B[2048,4096] fp32 -> out[4096,4096] fp32
// R4: 3 launches. GEMM reverted to R2's verified 0-conflict structure
//     (mfma_i32_16x16x64_i8, 128x128 block, BK=128, 3-bit XOR swizzle,
//     XCD L2 regioning) + __launch_bounds__(256,4) for 4 blocks/CU
//     (60 VGPR + 64 AGPR = 124 <= 128/wave) + nontemporal output stores.
// ---------------------------------------------------------------------------

#define M_DIM 4096
#define K_DIM 2048
#define N_DIM 4096

using int4v = __attribute__((ext_vector_type(4))) int;

typedef __attribute__((address_space(1))) const void glb_cv;
typedef __attribute__((address_space(3))) void lds_v;

__device__ __forceinline__ int qbyte(float x, float rs, float z) {
    // reference: clip(round(x/scale) + zero, 0, 255), shifted by -128
    float q = fminf(fmaxf(rintf(x * rs) + z, 0.0f), 255.0f);
    return (int)q - 128;
}

__device__ __forceinline__ int sum4(int w) {
    return (int)(signed char)(w) + (int)(signed char)(w >> 8) +
           (int)(signed char)(w >> 16) + (int)(signed char)(w >> 24);
}

// ---- Kernel 1: per-block min/max partials (512 A + 512 B); zero colB ----
__global__ void minmax_stage1(const float* __restrict__ A,
                              const float* __restrict__ B,
                              float* __restrict__ partials,
                              int* __restrict__ colB) {
    int b = blockIdx.x;
    if (b < 16) colB[b * 256 + threadIdx.x] = 0;  // init for quant atomics
    const float* src = (b < 512) ? A : B;
    int lb = (b < 512) ? b : b - 512;
    const float4* v = (const float4*)src + (long)lb * 4096;  // 4096 float4/block
    float mn = INFINITY, mx = -INFINITY;
    for (int i = threadIdx.x; i < 4096; i += 256) {
        float4 x = v[i];
        mn = fminf(mn, fminf(fminf(x.x, x.y), fminf(x.z, x.w)));
        mx = fmaxf(mx, fmaxf(fmaxf(x.x, x.y), fmaxf(x.z, x.w)));
    }
    for (int off = 32; off; off >>= 1) {
        mn = fminf(mn, __shfl_down(mn, off));
        mx = fmaxf(mx, __shfl_down(mx, off));
    }
    __shared__ float smn[4], smx[4];
    int w = threadIdx.x >> 6;
    if ((threadIdx.x & 63) == 0) { smn[w] = mn; smx[w] = mx; }
    __syncthreads();
    if (threadIdx.x == 0) {
        mn = fminf(fminf(smn[0], smn[1]), fminf(smn[2], smn[3]));
        mx = fmaxf(fmaxf(smx[0], smx[1]), fmaxf(smx[2], smx[3]));
        partials[2 * b] = mn;
        partials[2 * b + 1] = mx;
    }
}

// ---- Kernel 2: fused quantize. Blocks 0..2047: A (2 rows each, row-major
// i8, + row sums). Blocks 2048..4095: B 64x64 tile transpose (+ col sums).
// Every block deterministically re-reduces all partials -> identical qp.
__global__ void quant_fused(const float* __restrict__ A,
                            const float* __restrict__ B,
                            const float* __restrict__ partials,
                            signed char* __restrict__ A8,
                            signed char* __restrict__ B8T,
                            int* __restrict__ rowA,
                            int* __restrict__ colB,
                            float* __restrict__ qp) {
    int b = blockIdx.x, t = threadIdx.x;

    // -- reduce all 1024 partial pairs (L2/L3-cached after kernel 1) --
    float mnA = INFINITY, mxA = -INFINITY, mnB = INFINITY, mxB = -INFINITY;
    for (int i = t; i < 512; i += 256) {
        mnA = fminf(mnA, partials[2 * i]);
        mxA = fmaxf(mxA, partials[2 * i + 1]);
        mnB = fminf(mnB, partials[2 * (i + 512)]);
        mxB = fmaxf(mxB, partials[2 * (i + 512) + 1]);
    }
    for (int off = 32; off; off >>= 1) {
        mnA = fminf(mnA, __shfl_down(mnA, off));
        mxA = fmaxf(mxA, __shfl_down(mxA, off));
        mnB = fminf(mnB, __shfl_down(mnB, off));
        mxB = fmaxf(mxB, __shfl_down(mxB, off));
    }
    __shared__ float sred[4][4];
    int w = t >> 6;
    if ((t & 63) == 0) { sred[w][0] = mnA; sred[w][1] = mxA; sred[w][2] = mnB; sred[w][3] = mxB; }
    __syncthreads();
    mnA = fminf(fminf(sred[0][0], sred[1][0]), fminf(sred[2][0], sred[3][0]));
    mxA = fmaxf(fmaxf(sred[0][1], sred[1][1]), fmaxf(sred[2][1], sred[3][1]));
    mnB = fminf(fminf(sred[0][2], sred[1][2]), fminf(sred[2][2], sred[3][2]));
    mxB = fmaxf(fmaxf(sred[0][3], sred[1][3]), fmaxf(sred[2][3], sred[3][3]));
    float sA = (mxA - mnA) / 255.0f;
    float zA = rintf(-mnA / sA);
    float sB = (mxB - mnB) / 255.0f;
    float zB = rintf(-mnB / sB);
    if (b == 0 && t == 0) { qp[0] = sA; qp[1] = zA; qp[2] = sB; qp[3] = zB; }
    __syncthreads();

    if (b < 2048) {
        // ---- A path: 2 rows of 2048, fused row sums ----
        float rs = 1.0f / sA, z = zA;
        long base = (long)b * 4096 + (long)t * 16;
        const float4* v = (const float4*)(A + base);
        union { signed char c[16]; int4 i4; } u;
        int ls = 0;
#pragma unroll
        for (int j = 0; j < 4; j++) {
            float4 x = v[j];
            int q0 = qbyte(x.x, rs, z), q1 = qbyte(x.y, rs, z);
            int q2 = qbyte(x.z, rs, z), q3 = qbyte(x.w, rs, z);
            u.c[j * 4 + 0] = (signed char)q0;
            u.c[j * 4 + 1] = (signed char)q1;
            u.c[j * 4 + 2] = (signed char)q2;
            u.c[j * 4 + 3] = (signed char)q3;
            ls += q0 + q1 + q2 + q3;
        }
        *(int4*)(A8 + base) = u.i4;
        for (int off = 32; off; off >>= 1) ls += __shfl_down(ls, off);
        __shared__ int wsum[4];
        if ((t & 63) == 0) wsum[t >> 6] = ls;
        __syncthreads();
        if (t == 0) rowA[b * 2] = wsum[0] + wsum[1];
        if (t == 128) rowA[b * 2 + 1] = wsum[2] + wsum[3];
    } else {
        // ---- B path: 64x64 tile transpose via int-packed LDS, col sums ----
        float rs = 1.0f / sB, z = zB;
        int bb = b - 2048;
        int k0 = (bb & 31) * 64, n0 = (bb >> 5) * 64;
        __shared__ int tile[64][17];  // [n][k/4], +1 pad
        int cn = (t & 15) * 4;  // n offset within tile
        int kg = (t >> 4) * 4;  // k offset within tile
        int w0 = 0, w1 = 0, w2 = 0, w3 = 0;
#pragma unroll
        for (int r = 0; r < 4; r++) {
            float4 x = *(const float4*)&B[(long)(k0 + kg + r) * N_DIM + n0 + cn];
            w0 |= (qbyte(x.x, rs, z) & 255) << (8 * r);
            w1 |= (qbyte(x.y, rs, z) & 255) << (8 * r);
            w2 |= (qbyte(x.z, rs, z) & 255) << (8 * r);
            w3 |= (qbyte(x.w, rs, z) & 255) << (8 * r);
        }
        int kc = kg >> 2;
        tile[cn + 0][kc] = w0;
        tile[cn + 1][kc] = w1;
        tile[cn + 2][kc] = w2;
        tile[cn + 3][kc] = w3;
        __syncthreads();
        int n2 = t >> 2, kb = (t & 3) * 4;
        int4 v;
        v.x = tile[n2][kb + 0];
        v.y = tile[n2][kb + 1];
        v.z = tile[n2][kb + 2];
        v.w = tile[n2][kb + 3];
        *(int4*)&B8T[(long)(n0 + n2) * K_DIM + k0 + (t & 3) * 16] = v;
        int ls = sum4(v.x) + sum4(v.y) + sum4(v.z) + sum4(v.w);
        ls += __shfl_down(ls, 2);
        ls += __shfl_down(ls, 1);
        if ((t & 3) == 0) atomicAdd(&colB[n0 + n2], ls);
    }
}

// ---- Kernel 3: i8 MFMA GEMM (R2 structure, 4 blocks/CU) ----
// 128x128 block, BK=128, 4 waves each 64x64 (4x4 frags of 16x16x64).
// LDS: 16B chunk c of row r stored at slot c ^ (r&7) (3-bit XOR swizzle;
// this exact read geometry measured 0 bank conflicts in R2).
// Block->tile: 16 regions of 8x8 tiles keyed to XCD for L2 locality.
__global__ __launch_bounds__(256, 4) void gemm_i8(
        const signed char* __restrict__ A8,
        const signed char* __restrict__ B8T,
        const int* __restrict__ rowA,
        const int* __restrict__ colB,
        const float* __restrict__ qp,
        float* __restrict__ out) {
    __shared__ __align__(16) signed char As[128 * 128];  // 16 KB
    __shared__ __align__(16) signed char Bs[128 * 128];  // 16 KB

    // L2-locality block swizzle
    int b = blockIdx.x;
    int xcd = b & 7, i0 = b >> 3;
    int reg = xcd + 8 * (i0 >> 6);    // region 0..15
    int jj0 = i0 & 63;                // 0..63 within region
    int mt = (reg >> 2) * 8 + (jj0 >> 3);
    int nt = (reg & 3) * 8 + (jj0 & 7);
    int r0 = mt * 128, c0 = nt * 128;

    int t = threadIdx.x, lane = t & 63, wave = t >> 6;
    int mrow = lane & 15;
    int g = lane >> 4;               // k-group 0..3
    int wm = (wave >> 1) * 64;       // wave m offset
    int wn = (wave & 1) * 64;        // wave n offset

    int4v acc[4][4];
#pragma unroll
    for (int i = 0; i < 4; i++)
#pragma unroll
        for (int jj = 0; jj < 4; jj++) acc[i][jj] = (int4v){0, 0, 0, 0};

    // Staging offsets: LDS chunk ch -> row=ch>>3, slot p=ch&7 holds global
    // chunk p ^ (row&7).
    long aoff[4], boff[4];
#pragma unroll
    for (int jj = 0; jj < 4; jj++) {
        int ch = t + 256 * jj;       // 0..1023
        int row = ch >> 3, p = ch & 7;
        int gk = p ^ (row & 7);
        aoff[jj] = (long)(r0 + row) * K_DIM + gk * 16;
        boff[jj] = (long)(c0 + row) * K_DIM + gk * 16;
    }

    int swz = (mrow & 7);            // read-side XOR

    for (int k0 = 0; k0 < K_DIM; k0 += 128) {
        __syncthreads();  // protect LDS from previous iteration's readers
#pragma unroll
        for (int jj = 0; jj < 4; jj++)
            __builtin_amdgcn_global_load_lds((glb_cv*)(A8 + aoff[jj] + k0),
                                             (lds_v*)(As + (t + 256 * jj) * 16), 16, 0, 0);
#pragma unroll
        for (int jj = 0; jj < 4; jj++)
            __builtin_amdgcn_global_load_lds((glb_cv*)(B8T + boff[jj] + k0),
                                             (lds_v*)(Bs + (t + 256 * jj) * 16), 16, 0, 0);
        __syncthreads();  // staged data visible

#pragma unroll
        for (int ks = 0; ks < 2; ks++) {
            int c = ks * 4 + g;
            int koff = (c ^ swz) * 16;
            int4v af[4], bf[4];
#pragma unroll
            for (int i = 0; i < 4; i++)
                af[i] = *(const int4v*)&As[(wm + i * 16 + mrow) * 128 + koff];
#pragma unroll
            for (int jj = 0; jj < 4; jj++)
                bf[jj] = *(const int4v*)&Bs[(wn + jj * 16 + mrow) * 128 + koff];
#pragma unroll
            for (int i = 0; i < 4; i++)
#pragma unroll
                for (int jj = 0; jj < 4; jj++)
                    acc[i][jj] = __builtin_amdgcn_mfma_i32_16x16x64_i8(af[i], bf[jj], acc[i][jj], 0, 0, 0);
        }
    }

    // Epilogue: out = sA*sB*(acc + cB*rowA[m] + cA*colB[n] + K*cA*cB)
    float sA = qp[0], zA = qp[1], sB = qp[2], zB = qp[3];
    int cA = 128 - (int)zA, cB = 128 - (int)zB;
    float ss = sA * sB;
    int Kzz = K_DIM * cA * cB;
    int ocol = c0 + wn + mrow;
    int orow = r0 + wm + g * 4;
#pragma unroll
    for (int i = 0; i < 4; i++) {
        int ra[4];
#pragma unroll
        for (int rr = 0; rr < 4; rr++) ra[rr] = cB * rowA[orow + i * 16 + rr] + Kzz;
#pragma unroll
        for (int jj = 0; jj < 4; jj++) {
            int cc = ocol + jj * 16;
            int can = cA * colB[cc];
#pragma unroll
            for (int rr = 0; rr < 4; rr++) {
                int v = acc[i][jj][rr] + ra[rr] + can;
                __builtin_nontemporal_store(ss * (float)v,
                                            &out[(long)(orow + i * 16 + rr) * N_DIM + cc]);
            }
        }
    }
}

extern "C" void kernel_launch(void* const* d_in, const int* in_sizes, int n_in,
                              void* d_out, int out_size, void* d_ws, size_t ws_size,
                              hipStream_t stream) {
    const float* A = (const float*)d_in[0];
    const float* B = (const float*)d_in[1];
    float* out = (float*)d_out;
    char* ws = (char*)d_ws;

    signed char* A8  = (signed char*)ws;                    //  8 MB
    signed char* B8T = (signed char*)(ws + 8388608);        //  8 MB
    int*   rowA      = (int*)(ws + 16777216);               // 16 KB
    int*   colB      = (int*)(ws + 16793600);               // 16 KB
    float* partials  = (float*)(ws + 16809984);             //  8 KB
    float* qp        = (float*)(ws + 16818176);             // 16 B

    minmax_stage1<<<1024, 256, 0, stream>>>(A, B, partials, colB);
    quant_fused<<<4096, 256, 0, stream>>>(A, B, partials, A8, B8T, rowA, colB, qp);
    gemm_i8<<<1024, 256, 0, stream>>>(A8, B8T, rowA, colB, qp, out);
}